// Round 8
// baseline (5136.708 us; speedup 1.0000x reference)
//
#include <hip/hip_runtime.h>
#include <math.h>

// Problem constants: D=3, H=64, WIN=8, OUT=32, B=128, T=129
#define BB 128
#define TT 129
#define NSTEP 128
#define NW 16
#define WINW 8
#define OUTD 32

typedef _Float16 h2_t __attribute__((ext_vector_type(2)));

__device__ __forceinline__ float fast_rcp(float v){ return __builtin_amdgcn_rcpf(v); }
__device__ __forceinline__ float softplus_f(float v){ return fmaxf(v,0.f)+__logf(1.f+__expf(-fabsf(v))); }
__device__ __forceinline__ float sigmoid_f(float v){ return fast_rcp(1.f+__expf(-v)); }
__device__ __forceinline__ float tanh_f(float v){
    float ax=fminf(fabsf(v),15.f); float e=__expf(2.f*ax);
    float r=1.f-2.f*fast_rcp(e+1.f); return copysignf(r,v);
}
__device__ __forceinline__ float pack2(float a,float b){
    h2_t h; h.x=(_Float16)a; h.y=(_Float16)b; return __builtin_bit_cast(float,h);
}
__device__ __forceinline__ float dot2c(float wc,float ac,float acc){
    return __builtin_amdgcn_fdot2(__builtin_bit_cast(h2_t,wc),__builtin_bit_cast(h2_t,ac),acc,false);
}
__device__ __forceinline__ float dot2q(float4 wq,float4 aq,float acc){
    acc=dot2c(wq.x,aq.x,acc); acc=dot2c(wq.y,aq.y,acc);
    acc=dot2c(wq.z,aq.z,acc); acc=dot2c(wq.w,aq.w,acc); return acc;
}
__device__ __forceinline__ float4 packrow8(const float4* p, int k){
    // pack fp32 elements 8k..8k+7 of a row into one fp16-carrier float4
    float4 a=p[2*k], c=p[2*k+1];
    float4 r; r.x=pack2(a.x,a.y); r.y=pack2(a.z,a.w); r.z=pack2(c.x,c.y); r.w=pack2(c.z,c.w);
    return r;
}
#define DOT4(acc,Wv,Av) acc += (Wv).x*(Av).x + (Wv).y*(Av).y + (Wv).z*(Av).z + (Wv).w*(Av).w
#define PIN4(q) asm volatile("" : "+v"((q).x), "+v"((q).y), "+v"((q).z), "+v"((q).w))

// ONE WAVE per batch element: 64 threads, zero barriers (intra-wave LDS is in-order).
__global__ __launch_bounds__(64, 1)
void ncde_solve(const float* __restrict__ ts, const float* __restrict__ x,
                const float* __restrict__ W0, const float* __restrict__ b0,
                const float* __restrict__ W1, const float* __restrict__ b1,
                const float* __restrict__ W2, const float* __restrict__ b2,
                const float* __restrict__ V0, const float* __restrict__ c0,
                const float* __restrict__ V1, const float* __restrict__ c1,
                const float* __restrict__ V2, const float* __restrict__ c2,
                const float* __restrict__ R, const float* __restrict__ rb,
                float* __restrict__ out)
{
    const int b = blockIdx.x;
    const int lane = threadIdx.x;

    __shared__ __align__(16) float ya[32], y2a[32];        // y as 64 fp16 halves
    __shared__ __align__(16) float a0p[64], a1p[64];       // 128 halves each
    __shared__ __align__(16) float mp[96];                 // 192 halves
    __shared__ __align__(16) float u0p[3][64], u1p[3][64]; // 128 halves each
    __shared__ __align__(16) float RSh[1024];              // R 32x64 as fp16 carriers
    __shared__ float slopesSh[NW][6];
    __shared__ float dtsSh[NSTEP];
    __shared__ __align__(16) float scrA[128], scrB[128];   // fp32 init scratch

    // ---- per-lane full-row fp16 weight carriers (384 VGPRs) ----
    // V0/V1: rows 2l,2l+1 ; V2: rows l, 64+l, 128+l (S7 becomes lane-local)
    float4 w0r[2][8], w1r[2][16], w2r[3][16];
    #pragma unroll
    for (int r=0;r<2;r++){
        const float4* p = (const float4*)(V0 + (2*lane+r)*64);
        #pragma unroll
        for (int k=0;k<8;k++) w0r[r][k] = packrow8(p,k);
    }
    #pragma unroll
    for (int r=0;r<2;r++){
        const float4* p = (const float4*)(V1 + (2*lane+r)*128);
        #pragma unroll
        for (int k=0;k<16;k++) w1r[r][k] = packrow8(p,k);
    }
    #pragma unroll
    for (int j=0;j<3;j++){
        const float4* p = (const float4*)(V2 + (j*64+lane)*128);
        #pragma unroll
        for (int k=0;k<16;k++) w2r[j][k] = packrow8(p,k);
    }
    #pragma unroll
    for (int r=0;r<2;r++){ 
        #pragma unroll
        for (int k=0;k<8;k++) PIN4(w0r[r][k]);
        #pragma unroll
        for (int k=0;k<16;k++) PIN4(w1r[r][k]);
    }
    #pragma unroll
    for (int j=0;j<3;j++){
        #pragma unroll
        for (int k=0;k<16;k++) PIN4(w2r[j][k]);
    }
    const float c00=c0[2*lane], c01=c0[2*lane+1];
    const float c10=c1[2*lane], c11=c1[2*lane+1];
    const float c20=c2[lane],  c21=c2[64+lane], c22=c2[128+lane];
    const float rbp = rb[lane & 31];

    // R packed to fp16 carriers (1024 dwords; 16 per lane)
    #pragma unroll
    for (int i=0;i<16;i++){
        int idx = lane*16 + i;
        RSh[idx] = pack2(R[2*idx], R[2*idx+1]);
    }
    const float* tsb = ts + b*TT;
    for (int i=lane;i<NSTEP;i+=64) dtsSh[i] = tsb[i+1]-tsb[i];

    // ---- log-signature slopes (lanes 0..15, one window each) ----
    if (lane < NW) {
        const int w = lane;
        const float* xs = x + (size_t)(b*TT + w*WINW)*3;
        float x0c[3] = {xs[0], xs[1], xs[2]};
        float prev[3] = {x0c[0], x0c[1], x0c[2]};
        float am01=0.f, am02=0.f, am12=0.f, am10=0.f, am20=0.f, am21=0.f;
        #pragma unroll
        for (int k=0;k<WINW;k++) {
            float cur[3] = {xs[(k+1)*3+0], xs[(k+1)*3+1], xs[(k+1)*3+2]};
            float rel[3], dv[3];
            #pragma unroll
            for (int c=0;c<3;c++){ rel[c]=prev[c]-x0c[c]; dv[c]=cur[c]-prev[c]; }
            am01 += rel[0]*dv[1]; am10 += rel[1]*dv[0];
            am02 += rel[0]*dv[2]; am20 += rel[2]*dv[0];
            am12 += rel[1]*dv[2]; am21 += rel[2]*dv[1];
            prev[0]=cur[0]; prev[1]=cur[1]; prev[2]=cur[2];
        }
        const float invden = 1.f/(tsb[(w+1)*WINW] - tsb[w*WINW]);
        slopesSh[w][0] = (prev[0]-x0c[0])*invden;
        slopesSh[w][1] = (prev[1]-x0c[1])*invden;
        slopesSh[w][2] = (prev[2]-x0c[2])*invden;
        slopesSh[w][3] = 0.5f*(am01-am10)*invden;
        slopesSh[w][4] = 0.5f*(am02-am20)*invden;
        slopesSh[w][5] = 0.5f*(am12-am21)*invden;
    }

    // ---- h0 = init_mlp(x[b,0,:]) (fp32, global-streamed, wave-sync LDS) ----
    float y;
    {
        const float xv0 = x[(size_t)b*TT*3+0];
        const float xv1 = x[(size_t)b*TT*3+1];
        const float xv2 = x[(size_t)b*TT*3+2];
        #pragma unroll
        for (int r=0;r<2;r++){
            int row = 2*lane+r;
            float acc = b0[row] + W0[row*3]*xv0 + W0[row*3+1]*xv1 + W0[row*3+2]*xv2;
            scrA[row] = softplus_f(acc);
        }
        #pragma unroll
        for (int r=0;r<2;r++){
            int row = 2*lane+r;
            float acc = b1[row];
            const float4* wr = (const float4*)(W1 + row*128);
            #pragma unroll 8
            for (int k=0;k<32;k++){ float4 wv=wr[k]; float4 av=((const float4*)scrA)[k]; DOT4(acc,wv,av); }
            scrB[row] = softplus_f(acc);
        }
        float acc = b2[lane];
        const float4* wr = (const float4*)(W2 + lane*128);
        #pragma unroll 8
        for (int k=0;k<32;k++){ float4 wv=wr[k]; float4 av=((const float4*)scrB)[k]; DOT4(acc,wv,av); }
        y = acc;
        ((_Float16*)ya)[lane] = (_Float16)y;
    }

    float k1 = 0.f;

    // ---- F(y): zero barriers; LDS broadcast reads, in-order intra-wave ----
    auto Feval = [&](const float* yin, bool first, float dt,
                     float s0,float s1,float s2,float s3,float s4,float s5) {
        float sg0a, sg0b, sg1a, sg1b, mm0, mm1, mm2, dt0, dt1, dt2;
        // S1: z0 = V0@y + c0 (rows 2l,2l+1; K=64 = 8 carriers)
        {
            const float4* yb = (const float4*)yin;
            float zA0=0,zB0=0,zA1=0,zB1=0;
            #pragma unroll
            for (int k=0;k<4;k++){ float4 a=yb[k]; zA0=dot2q(w0r[0][k],a,zA0); zA1=dot2q(w0r[1][k],a,zA1); }
            #pragma unroll
            for (int k=4;k<8;k++){ float4 a=yb[k]; zB0=dot2q(w0r[0][k],a,zB0); zB1=dot2q(w0r[1][k],a,zB1); }
            float z0=zA0+zB0+c00, z1=zA1+zB1+c01;
            sg0a=sigmoid_f(z0); sg0b=sigmoid_f(z1);
            a0p[lane]=pack2(softplus_f(z0), softplus_f(z1));
        }
        // S2: z1 = V1@a0 + c1 (rows 2l,2l+1; K=128 = 16 carriers)
        {
            const float4* ab = (const float4*)a0p;
            float zA0=0,zB0=0,zA1=0,zB1=0;
            #pragma unroll
            for (int k=0;k<8;k++){  float4 a=ab[k]; zA0=dot2q(w1r[0][k],a,zA0); zA1=dot2q(w1r[1][k],a,zA1); }
            #pragma unroll
            for (int k=8;k<16;k++){ float4 a=ab[k]; zB0=dot2q(w1r[0][k],a,zB0); zB1=dot2q(w1r[1][k],a,zB1); }
            float z0=zA0+zB0+c10, z1=zA1+zB1+c11;
            sg1a=sigmoid_f(z0); sg1b=sigmoid_f(z1);
            a1p[lane]=pack2(softplus_f(z0), softplus_f(z1));
        }
        // S3: z2 = V2@a1 + c2 (rows l,64+l,128+l) ; m=tanh, dtan in regs
        {
            const float4* ab = (const float4*)a1p;
            float zA0=0,zB0=0,zA1=0,zB1=0,zA2=0,zB2=0;
            #pragma unroll
            for (int k=0;k<8;k++){  float4 a=ab[k]; zA0=dot2q(w2r[0][k],a,zA0); zA1=dot2q(w2r[1][k],a,zA1); zA2=dot2q(w2r[2][k],a,zA2); }
            #pragma unroll
            for (int k=8;k<16;k++){ float4 a=ab[k]; zB0=dot2q(w2r[0][k],a,zB0); zB1=dot2q(w2r[1][k],a,zB1); zB2=dot2q(w2r[2][k],a,zB2); }
            float z0=zA0+zB0+c20, z1=zA1+zB1+c21, z2=zA2+zB2+c22;
            mm0=tanh_f(z0); mm1=tanh_f(z1); mm2=tanh_f(z2);
            dt0=1.f-mm0*mm0; dt1=1.f-mm1*mm1; dt2=1.f-mm2*mm2;
            _Float16* mh=(_Float16*)mp;
            mh[lane]=(_Float16)mm0; mh[64+lane]=(_Float16)mm1; mh[128+lane]=(_Float16)mm2;
        }
        // S4: u0[d] = sig0 * (V0 @ m[d])  (m[d]: 8 carriers at mp+8d)
        #pragma unroll
        for (int d=0;d<3;d++){
            const float4* md = (const float4*)mp + d*2; // 8 float4 = idx d*8.. -> (float4*)mp + d*2? NO
            md = ((const float4*)mp) + d*2;             // placeholder, fixed below
            const float4* mv = ((const float4*)mp) + d*2;
            (void)md; (void)mv;
            const float4* m4 = (const float4*)(mp + d*32); // d*32 floats = d*8 float4 = 64 halves
            float tA0=0,tB0=0,tA1=0,tB1=0;
            #pragma unroll
            for (int k=0;k<4;k++){ float4 a=m4[k]; tA0=dot2q(w0r[0][k],a,tA0); tA1=dot2q(w0r[1][k],a,tA1); }
            #pragma unroll
            for (int k=4;k<8;k++){ float4 a=m4[k]; tB0=dot2q(w0r[0][k],a,tB0); tB1=dot2q(w0r[1][k],a,tB1); }
            u0p[d][lane]=pack2(sg0a*(tA0+tB0), sg0b*(tA1+tB1));
        }
        // S5: u1[d] = sig1 * (V1 @ u0[d])
        #pragma unroll
        for (int d=0;d<3;d++){
            const float4* q = (const float4*)&u0p[d][0];
            float tA0=0,tB0=0,tA1=0,tB1=0;
            #pragma unroll
            for (int k=0;k<8;k++){  float4 a=q[k]; tA0=dot2q(w1r[0][k],a,tA0); tA1=dot2q(w1r[1][k],a,tA1); }
            #pragma unroll
            for (int k=8;k<16;k++){ float4 a=q[k]; tB0=dot2q(w1r[0][k],a,tB0); tB1=dot2q(w1r[1][k],a,tB1); }
            u1p[d][lane]=pack2(sg1a*(tA0+tB0), sg1b*(tA1+tB1));
        }
        // S6: Jf[d][j] = dtan_j * (V2_rowj @ u1[d]) — all lane-local
        float Jf[3][3];
        #pragma unroll
        for (int d=0;d<3;d++){
            const float4* q = (const float4*)&u1p[d][0];
            float tA0=0,tB0=0,tA1=0,tB1=0,tA2=0,tB2=0;
            #pragma unroll
            for (int k=0;k<8;k++){  float4 a=q[k]; tA0=dot2q(w2r[0][k],a,tA0); tA1=dot2q(w2r[1][k],a,tA1); tA2=dot2q(w2r[2][k],a,tA2); }
            #pragma unroll
            for (int k=8;k<16;k++){ float4 a=q[k]; tB0=dot2q(w2r[0][k],a,tB0); tB1=dot2q(w2r[1][k],a,tB1); tB2=dot2q(w2r[2][k],a,tB2); }
            Jf[d][0]=dt0*(tA0+tB0); Jf[d][1]=dt1*(tA1+tB1); Jf[d][2]=dt2*(tA2+tB2);
        }
        // S7 + Heun (fully lane-local: k[lane])
        float kk = mm0*s0 + mm1*s1 + mm2*s2
                 + s3*(Jf[0][1]-Jf[1][0])
                 + s4*(Jf[0][2]-Jf[2][0])
                 + s5*(Jf[1][2]-Jf[2][1]);
        if (first){
            k1 = kk;
            float y2v = y + dt*kk;
            ((_Float16*)y2a)[lane] = (_Float16)y2v;
        } else {
            y = y + 0.5f*dt*(k1 + kk);
            ((_Float16*)ya)[lane] = (_Float16)y;
        }
    };

    // ---- Heun scan ----
    for (int step=0; step<NSTEP; ++step) {
        const int w = step >> 3;
        const float s0=slopesSh[w][0], s1=slopesSh[w][1], s2=slopesSh[w][2],
                    s3=slopesSh[w][3], s4=slopesSh[w][4], s5=slopesSh[w][5];
        const float dt = dtsSh[step];
        // projection of current y (rows 0..31 on lanes 0..31; fp16 R,y)
        if (lane < OUTD) {
            const float4* rr = (const float4*)(RSh + lane*32);
            const float4* yb = (const float4*)ya;
            float pa=0.f, pb=0.f;
            #pragma unroll
            for (int k=0;k<4;k++){ pa=dot2q(rr[k],yb[k],pa); }
            #pragma unroll
            for (int k=4;k<8;k++){ pb=dot2q(rr[k],yb[k],pb); }
            out[(size_t)(b*TT + step)*OUTD + lane] = tanh_f(pa+pb+rbp);
        }
        Feval(ya,  true,  dt, s0,s1,s2,s3,s4,s5);
        Feval(y2a, false, dt, s0,s1,s2,s3,s4,s5);
    }
    // final row T-1
    if (lane < OUTD) {
        const float4* rr = (const float4*)(RSh + lane*32);
        const float4* yb = (const float4*)ya;
        float pa=0.f, pb=0.f;
        #pragma unroll
        for (int k=0;k<4;k++){ pa=dot2q(rr[k],yb[k],pa); }
        #pragma unroll
        for (int k=4;k<8;k++){ pb=dot2q(rr[k],yb[k],pb); }
        out[(size_t)(b*TT + NSTEP)*OUTD + lane] = tanh_f(pa+pb+rbp);
    }
}

extern "C" void kernel_launch(void* const* d_in, const int* in_sizes, int n_in,
                              void* d_out, int out_size, void* d_ws, size_t ws_size,
                              hipStream_t stream) {
    const float* ts = (const float*)d_in[0];
    const float* x  = (const float*)d_in[1];
    const float* W0 = (const float*)d_in[2];
    const float* b0 = (const float*)d_in[3];
    const float* W1 = (const float*)d_in[4];
    const float* b1 = (const float*)d_in[5];
    const float* W2 = (const float*)d_in[6];
    const float* b2 = (const float*)d_in[7];
    const float* V0 = (const float*)d_in[8];
    const float* c0 = (const float*)d_in[9];
    const float* V1 = (const float*)d_in[10];
    const float* c1 = (const float*)d_in[11];
    const float* V2 = (const float*)d_in[12];
    const float* c2 = (const float*)d_in[13];
    const float* R  = (const float*)d_in[14];
    const float* rb = (const float*)d_in[15];
    float* out = (float*)d_out;

    ncde_solve<<<dim3(BB), dim3(64), 0, stream>>>(
        ts, x, W0, b0, W1, b1, W2, b2, V0, c0, V1, c1, V2, c2, R, rb, out);
}

// Round 9
// 2400.058 us; speedup vs baseline: 2.1402x; 2.1402x over previous
//
#include <hip/hip_runtime.h>
#include <math.h>

// Problem constants: D=3, H=64, WIN=8, OUT=32, B=128, T=129
#define BB 128
#define TT 129
#define NSTEP 128
#define NW 16
#define WINW 8
#define OUTD 32
#define GG 4    // batch elements per block (each on its own 256-thread group)

typedef _Float16 h2_t __attribute__((ext_vector_type(2)));

__device__ __forceinline__ float fast_rcp(float v){ return __builtin_amdgcn_rcpf(v); }
__device__ __forceinline__ float softplus_f(float v){ return fmaxf(v,0.f)+__logf(1.f+__expf(-fabsf(v))); }
__device__ __forceinline__ float sigmoid_f(float v){ return fast_rcp(1.f+__expf(-v)); }
__device__ __forceinline__ float tanh_f(float v){
    float ax=fminf(fabsf(v),15.f); float e=__expf(2.f*ax);
    float r=1.f-2.f*fast_rcp(e+1.f); return copysignf(r,v);
}
__device__ __forceinline__ float pack2(float a,float b){
    h2_t h; h.x=(_Float16)a; h.y=(_Float16)b; return __builtin_bit_cast(float,h);
}
__device__ __forceinline__ float dot2c(float wc,float ac,float acc){
    return __builtin_amdgcn_fdot2(__builtin_bit_cast(h2_t,wc),__builtin_bit_cast(h2_t,ac),acc,false);
}
__device__ __forceinline__ float dot2q(float4 wq,float4 aq,float acc){
    acc=dot2c(wq.x,aq.x,acc); acc=dot2c(wq.y,aq.y,acc);
    acc=dot2c(wq.z,aq.z,acc); acc=dot2c(wq.w,aq.w,acc); return acc;
}
#define DOT4(acc,Wv,Av) acc += (Wv).x*(Av).x + (Wv).y*(Av).y + (Wv).z*(Av).z + (Wv).w*(Av).w
#define PIN4(q) asm volatile("" : "+v"((q).x), "+v"((q).y), "+v"((q).z), "+v"((q).w))

// G=4 elements per 1024-thread block; 16 waves/CU -> VGPR cap 128 (R7 code used 108).
__global__ __launch_bounds__(1024, 1)
void ncde_solve(const float* __restrict__ ts, const float* __restrict__ x,
                const float* __restrict__ W0, const float* __restrict__ b0,
                const float* __restrict__ W1, const float* __restrict__ b1,
                const float* __restrict__ W2, const float* __restrict__ b2,
                const float* __restrict__ V0, const float* __restrict__ c0,
                const float* __restrict__ V1, const float* __restrict__ c1,
                const float* __restrict__ V2, const float* __restrict__ c2,
                const float* __restrict__ R, const float* __restrict__ rb,
                float* __restrict__ out)
{
    const int g   = threadIdx.x >> 8;        // group (batch element within block)
    const int tid = threadIdx.x & 255;       // thread within group
    const int b   = blockIdx.x * GG + g;
    const int row2 = tid >> 1, half = tid & 1;         // rows 0..127, K halved
    const int row4 = 128 + (tid >> 2), quad = tid & 3; // V2 rows 128..191, K quartered
    const int prow = tid >> 3, poct = tid & 7;         // projection

    __shared__ __align__(16) float RSh[OUTD*64];       // shared across groups (read-only)
    __shared__ __align__(16) float ySh[GG][64], k1Sh[GG][64];
    __shared__ __align__(16) float yp[GG][32], y2p[GG][32];     // y: 64 packed halves
    __shared__ __align__(16) float a0p[GG][64], a1p[GG][64];    // 128 packed halves each
    __shared__ __align__(16) float mp[GG][96];                  // 192 packed halves
    __shared__ __align__(16) float u0p[GG][3][64], u1p[GG][3][64];
    __shared__ float mSh[GG][192];
    __shared__ float JfSh[GG][3][192];
    __shared__ float slopesSh[GG][NW][6];
    __shared__ float dtsSh[GG][NSTEP];

    // ---- fp16-packed weight carriers in registers: 24 float4 = 96 VGPRs ----
    float4 v0p4[4];  // V0 half-row  (32 halves)
    float4 v1p4[8];  // V1 half-row  (64 halves)
    float4 v2p4[8];  // V2 rows 0..127 half-row (64 halves)
    float4 v2q4[4];  // V2 rows 128..191 quarter-row (32 halves), rotated groups
    {
        const float4* p0 = (const float4*)(V0 + row2*64 + half*32);
        #pragma unroll
        for (int k=0;k<4;k++){
            float4 a=p0[2*k], c=p0[2*k+1];
            float4 r; r.x=pack2(a.x,a.y); r.y=pack2(a.z,a.w); r.z=pack2(c.x,c.y); r.w=pack2(c.z,c.w);
            v0p4[k]=r;
        }
        const float4* p1 = (const float4*)(V1 + row2*128 + half*64);
        #pragma unroll
        for (int k=0;k<8;k++){
            float4 a=p1[2*k], c=p1[2*k+1];
            float4 r; r.x=pack2(a.x,a.y); r.y=pack2(a.z,a.w); r.z=pack2(c.x,c.y); r.w=pack2(c.z,c.w);
            v1p4[k]=r;
        }
        const float4* p2 = (const float4*)(V2 + row2*128 + half*64);
        #pragma unroll
        for (int k=0;k<8;k++){
            float4 a=p2[2*k], c=p2[2*k+1];
            float4 r; r.x=pack2(a.x,a.y); r.y=pack2(a.z,a.w); r.z=pack2(c.x,c.y); r.w=pack2(c.z,c.w);
            v2p4[k]=r;
        }
        #pragma unroll
        for (int j=0;j<4;j++){
            int gr=(quad+j)&3;
            const float4* pg = (const float4*)(V2 + row4*128 + quad*32 + gr*8);
            float4 a=pg[0], c=pg[1];
            float4 r; r.x=pack2(a.x,a.y); r.y=pack2(a.z,a.w); r.z=pack2(c.x,c.y); r.w=pack2(c.z,c.w);
            v2q4[j]=r;
        }
        #pragma unroll
        for (int k=0;k<4;k++) PIN4(v0p4[k]);
        #pragma unroll
        for (int k=0;k<8;k++) PIN4(v1p4[k]);
        #pragma unroll
        for (int k=0;k<8;k++) PIN4(v2p4[k]);
        #pragma unroll
        for (int k=0;k<4;k++) PIN4(v2q4[k]);
    }
    const float c0r = c0[row2], c1r = c1[row2], c2a = c2[row2], c2b = c2[row4];
    const float rbp = rb[prow];

    for (int i=threadIdx.x; i<OUTD*64; i+=1024) RSh[i] = R[i];
    const float* tsb = ts + b*TT;
    for (int i=tid; i<NSTEP; i+=256) dtsSh[g][i] = tsb[i+1] - tsb[i];

    // ---- log-signature slopes (16 lanes per group) ----
    if (tid < NW) {
        const int w = tid;
        const float* xs = x + (size_t)(b*TT + w*WINW)*3;
        float x0c[3] = {xs[0], xs[1], xs[2]};
        float prev[3] = {x0c[0], x0c[1], x0c[2]};
        float am01=0.f, am02=0.f, am12=0.f, am10=0.f, am20=0.f, am21=0.f;
        #pragma unroll
        for (int k=0;k<WINW;k++) {
            float cur[3] = {xs[(k+1)*3+0], xs[(k+1)*3+1], xs[(k+1)*3+2]};
            float rel[3], dv[3];
            #pragma unroll
            for (int c=0;c<3;c++){ rel[c]=prev[c]-x0c[c]; dv[c]=cur[c]-prev[c]; }
            am01 += rel[0]*dv[1]; am10 += rel[1]*dv[0];
            am02 += rel[0]*dv[2]; am20 += rel[2]*dv[0];
            am12 += rel[1]*dv[2]; am21 += rel[2]*dv[1];
            prev[0]=cur[0]; prev[1]=cur[1]; prev[2]=cur[2];
        }
        const float invden = 1.f/(tsb[(w+1)*WINW] - tsb[w*WINW]);
        slopesSh[g][w][0] = (prev[0]-x0c[0])*invden;
        slopesSh[g][w][1] = (prev[1]-x0c[1])*invden;
        slopesSh[g][w][2] = (prev[2]-x0c[2])*invden;
        slopesSh[g][w][3] = 0.5f*(am01-am10)*invden;
        slopesSh[g][w][4] = 0.5f*(am02-am20)*invden;
        slopesSh[g][w][5] = 0.5f*(am12-am21)*invden;
    }

    // ---- h0 = init_mlp(x[b,0,:]) (one-time, fp32, global-streamed; mSh/JfSh as scratch) ----
    if (tid < 128) {
        const float xv0 = x[(size_t)b*TT*3+0];
        const float xv1 = x[(size_t)b*TT*3+1];
        const float xv2 = x[(size_t)b*TT*3+2];
        float acc = b0[tid] + W0[tid*3]*xv0 + W0[tid*3+1]*xv1 + W0[tid*3+2]*xv2;
        mSh[g][tid] = softplus_f(acc);
    }
    __syncthreads();
    if (tid < 128) {
        float acc = b1[tid];
        const float4* r = (const float4*)(W1 + tid*128);
        #pragma unroll 8
        for (int k=0;k<32;k++){ float4 wv=r[k]; float4 av=*(const float4*)&mSh[g][4*k]; DOT4(acc,wv,av); }
        JfSh[g][0][tid] = softplus_f(acc);
    }
    __syncthreads();
    if (tid < 64) {
        float acc = b2[tid];
        const float4* r = (const float4*)(W2 + tid*128);
        #pragma unroll 8
        for (int k=0;k<32;k++){ float4 wv=r[k]; float4 av=*(const float4*)&JfSh[g][0][4*k]; DOT4(acc,wv,av); }
        ySh[g][tid] = acc;
        float p = __shfl_xor(acc, 1, 64);
        if (!(tid & 1)) yp[g][tid>>1] = pack2(acc, p);
    }
    __syncthreads();

    // per-lane activation-derivative registers (producer lane == consumer lane)
    float sig0r=0.f, sig1r=0.f, dtanAr=0.f, dtanBr=0.f;

    // ---- F(y): fp16 inner, fp32 feedback (y, k, S7 combine) ----
    auto Feval = [&](const float* ypIn, bool first, float dt, int w) {
        // S1: z0 = V0@y + c0
        {
            float zA=0.f, zB=0.f;
            const float4* yb = (const float4*)ypIn + half*4;
            zA=dot2q(v0p4[0],yb[0],zA); zB=dot2q(v0p4[1],yb[1],zB);
            zA=dot2q(v0p4[2],yb[2],zA); zB=dot2q(v0p4[3],yb[3],zB);
            float z = zA + zB;
            z += __shfl_xor(z, 1, 64);
            z += c0r;
            float a = softplus_f(z);
            sig0r = sigmoid_f(z);
            if (!half) ((_Float16*)&a0p[g][0])[row2] = (_Float16)a;
        }
        __syncthreads();
        // S2: z1 = V1@a0 + c1
        {
            float zA=0.f, zB=0.f;
            const float4* ab = (const float4*)&a0p[g][0] + half*8;
            #pragma unroll
            for (int k=0;k<4;k++){ zA=dot2q(v1p4[k],ab[k],zA); }
            #pragma unroll
            for (int k=4;k<8;k++){ zB=dot2q(v1p4[k],ab[k],zB); }
            float z = zA + zB;
            z += __shfl_xor(z, 1, 64);
            z += c1r;
            float a = softplus_f(z);
            sig1r = sigmoid_f(z);
            if (!half) ((_Float16*)&a1p[g][0])[row2] = (_Float16)a;
        }
        __syncthreads();
        // S3: z2 = V2@a1 + c2 ; m = tanh, dtan in regs
        {
            float zA=0.f, zB=0.f;
            const float4* ab = (const float4*)&a1p[g][0] + half*8;
            #pragma unroll
            for (int k=0;k<4;k++){ zA=dot2q(v2p4[k],ab[k],zA); }
            #pragma unroll
            for (int k=4;k<8;k++){ zB=dot2q(v2p4[k],ab[k],zB); }
            float z = zA + zB;
            z += __shfl_xor(z, 1, 64);
            z += c2a;
            float mm = tanh_f(z);
            dtanAr = 1.f - mm*mm;
            if (!half){ mSh[g][row2]=mm; ((_Float16*)&mp[g][0])[row2]=(_Float16)mm; }

            float zq = 0.f;
            const float4* a4 = (const float4*)&a1p[g][0];
            #pragma unroll
            for (int j=0;j<4;j++){ zq=dot2q(v2q4[j], a4[quad*4 + ((quad+j)&3)], zq); }
            zq += __shfl_xor(zq, 1, 64);
            zq += __shfl_xor(zq, 2, 64);
            zq += c2b;
            float mq = tanh_f(zq);
            dtanBr = 1.f - mq*mq;
            if (!quad){ mSh[g][row4]=mq; ((_Float16*)&mp[g][0])[row4]=(_Float16)mq; }
        }
        __syncthreads();
        // S4: u0[d] = sig0 * (V0 @ m[d])
        {
            float t0=0.f,t1=0.f,t2=0.f;
            const float4* m0 = (const float4*)&mp[g][0] + half*4;
            const float4* m1 = (const float4*)&mp[g][0] + 8  + half*4;
            const float4* m2 = (const float4*)&mp[g][0] + 16 + half*4;
            #pragma unroll
            for (int k=0;k<4;k++){ t0=dot2q(v0p4[k],m0[k],t0); t1=dot2q(v0p4[k],m1[k],t1); t2=dot2q(v0p4[k],m2[k],t2); }
            t0 += __shfl_xor(t0,1,64);
            t1 += __shfl_xor(t1,1,64);
            t2 += __shfl_xor(t2,1,64);
            if (!half){
                ((_Float16*)&u0p[g][0][0])[row2]=(_Float16)(sig0r*t0);
                ((_Float16*)&u0p[g][1][0])[row2]=(_Float16)(sig0r*t1);
                ((_Float16*)&u0p[g][2][0])[row2]=(_Float16)(sig0r*t2);
            }
        }
        __syncthreads();
        // S5: u1[d] = sig1 * (V1 @ u0[d])
        {
            float t0=0.f,t1=0.f,t2=0.f;
            const float4* q0 = (const float4*)&u0p[g][0][0] + half*8;
            const float4* q1 = (const float4*)&u0p[g][1][0] + half*8;
            const float4* q2 = (const float4*)&u0p[g][2][0] + half*8;
            #pragma unroll
            for (int k=0;k<8;k++){ t0=dot2q(v1p4[k],q0[k],t0); t1=dot2q(v1p4[k],q1[k],t1); t2=dot2q(v1p4[k],q2[k],t2); }
            t0 += __shfl_xor(t0,1,64);
            t1 += __shfl_xor(t1,1,64);
            t2 += __shfl_xor(t2,1,64);
            if (!half){
                ((_Float16*)&u1p[g][0][0])[row2]=(_Float16)(sig1r*t0);
                ((_Float16*)&u1p[g][1][0])[row2]=(_Float16)(sig1r*t1);
                ((_Float16*)&u1p[g][2][0])[row2]=(_Float16)(sig1r*t2);
            }
        }
        __syncthreads();
        // S6: Jf[d] = dtan * (V2 @ u1[d])
        {
            float t0=0.f,t1=0.f,t2=0.f;
            const float4* q0 = (const float4*)&u1p[g][0][0] + half*8;
            const float4* q1 = (const float4*)&u1p[g][1][0] + half*8;
            const float4* q2 = (const float4*)&u1p[g][2][0] + half*8;
            #pragma unroll
            for (int k=0;k<8;k++){ t0=dot2q(v2p4[k],q0[k],t0); t1=dot2q(v2p4[k],q1[k],t1); t2=dot2q(v2p4[k],q2[k],t2); }
            t0 += __shfl_xor(t0,1,64);
            t1 += __shfl_xor(t1,1,64);
            t2 += __shfl_xor(t2,1,64);
            if (!half){
                JfSh[g][0][row2]=dtanAr*t0; JfSh[g][1][row2]=dtanAr*t1; JfSh[g][2][row2]=dtanAr*t2;
            }
            float s0=0.f,s1=0.f,s2=0.f;
            const float4* w0 = (const float4*)&u1p[g][0][0];
            const float4* w1 = (const float4*)&u1p[g][1][0];
            const float4* w2 = (const float4*)&u1p[g][2][0];
            #pragma unroll
            for (int j=0;j<4;j++){
                const int idx = quad*4 + ((quad+j)&3);
                s0=dot2q(v2q4[j],w0[idx],s0); s1=dot2q(v2q4[j],w1[idx],s1); s2=dot2q(v2q4[j],w2[idx],s2);
            }
            s0 += __shfl_xor(s0,1,64); s0 += __shfl_xor(s0,2,64);
            s1 += __shfl_xor(s1,1,64); s1 += __shfl_xor(s1,2,64);
            s2 += __shfl_xor(s2,1,64); s2 += __shfl_xor(s2,2,64);
            if (!quad){
                JfSh[g][0][row4]=dtanBr*s0; JfSh[g][1][row4]=dtanBr*s1; JfSh[g][2][row4]=dtanBr*s2;
            }
        }
        __syncthreads();
        // S7 + Heun integrate (fp32, first wave of group) + fp16 y re-pack via shfl
        if (tid < 64) {
            const int h = tid;
            const float s0=slopesSh[g][w][0], s1=slopesSh[g][w][1], s2=slopesSh[g][w][2],
                        s3=slopesSh[g][w][3], s4=slopesSh[g][w][4], s5=slopesSh[g][w][5];
            float kk = mSh[g][h]*s0 + mSh[g][64+h]*s1 + mSh[g][128+h]*s2;
            kk += s3*(JfSh[g][0][64+h]  - JfSh[g][1][h]);
            kk += s4*(JfSh[g][0][128+h] - JfSh[g][2][h]);
            kk += s5*(JfSh[g][1][128+h] - JfSh[g][2][64+h]);
            if (first){
                k1Sh[g][h] = kk;
                float y2 = ySh[g][h] + dt*kk;
                float p = __shfl_xor(y2, 1, 64);
                if (!(h&1)) y2p[g][h>>1] = pack2(y2, p);
            } else {
                float yn = ySh[g][h] + 0.5f*dt*(k1Sh[g][h] + kk);
                ySh[g][h] = yn;
                float p = __shfl_xor(yn, 1, 64);
                if (!(h&1)) yp[g][h>>1] = pack2(yn, p);
            }
        }
        __syncthreads();
    };

    // ---- Heun scan; projection of y_step overlapped with S1 phase ----
    for (int step=0; step<NSTEP; ++step) {
        {
            float pacc = 0.f;
            const float4* rr = (const float4*)(RSh + prow*64 + poct*8);
            const float4* yy = (const float4*)(&ySh[g][0] + poct*8);
            DOT4(pacc, rr[0], yy[0]); DOT4(pacc, rr[1], yy[1]);
            pacc += __shfl_xor(pacc,1,64);
            pacc += __shfl_xor(pacc,2,64);
            pacc += __shfl_xor(pacc,4,64);
            if (!poct) out[(size_t)(b*TT + step)*OUTD + prow] = tanh_f(pacc + rbp);
        }
        const float dt = dtsSh[g][step];
        const int w = step >> 3;
        Feval(&yp[g][0],  true,  dt, w);
        Feval(&y2p[g][0], false, dt, w);
    }
    {
        float pacc = 0.f;
        const float4* rr = (const float4*)(RSh + prow*64 + poct*8);
        const float4* yy = (const float4*)(&ySh[g][0] + poct*8);
        DOT4(pacc, rr[0], yy[0]); DOT4(pacc, rr[1], yy[1]);
        pacc += __shfl_xor(pacc,1,64);
        pacc += __shfl_xor(pacc,2,64);
        pacc += __shfl_xor(pacc,4,64);
        if (!poct) out[(size_t)(b*TT + NSTEP)*OUTD + prow] = tanh_f(pacc + rbp);
    }
}

extern "C" void kernel_launch(void* const* d_in, const int* in_sizes, int n_in,
                              void* d_out, int out_size, void* d_ws, size_t ws_size,
                              hipStream_t stream) {
    const float* ts = (const float*)d_in[0];
    const float* x  = (const float*)d_in[1];
    const float* W0 = (const float*)d_in[2];
    const float* b0 = (const float*)d_in[3];
    const float* W1 = (const float*)d_in[4];
    const float* b1 = (const float*)d_in[5];
    const float* W2 = (const float*)d_in[6];
    const float* b2 = (const float*)d_in[7];
    const float* V0 = (const float*)d_in[8];
    const float* c0 = (const float*)d_in[9];
    const float* V1 = (const float*)d_in[10];
    const float* c1 = (const float*)d_in[11];
    const float* V2 = (const float*)d_in[12];
    const float* c2 = (const float*)d_in[13];
    const float* R  = (const float*)d_in[14];
    const float* rb = (const float*)d_in[15];
    float* out = (float*)d_out;

    ncde_solve<<<dim3(BB/GG), dim3(256*GG), 0, stream>>>(
        ts, x, W0, b0, W1, b1, W2, b2, V0, c0, V1, c1, V2, c2, R, rb, out);
}

// Round 10
// 1064.384 us; speedup vs baseline: 4.8260x; 2.2549x over previous
//
#include <hip/hip_runtime.h>
#include <math.h>

// Problem constants: D=3, H=64, WIN=8, OUT=32, B=128, T=129
#define BB 128
#define TT 129
#define NSTEP 128
#define NW 16
#define WINW 8
#define OUTD 32
#define GG 2    // batch elements per block (each on its own 256-thread group)

typedef _Float16 h2_t __attribute__((ext_vector_type(2)));

__device__ __forceinline__ float fast_rcp(float v){ return __builtin_amdgcn_rcpf(v); }
__device__ __forceinline__ float softplus_f(float v){ return fmaxf(v,0.f)+__logf(1.f+__expf(-fabsf(v))); }
__device__ __forceinline__ float sigmoid_f(float v){ return fast_rcp(1.f+__expf(-v)); }
__device__ __forceinline__ float tanh_f(float v){
    float ax=fminf(fabsf(v),15.f); float e=__expf(2.f*ax);
    float r=1.f-2.f*fast_rcp(e+1.f); return copysignf(r,v);
}
__device__ __forceinline__ float pack2(float a,float b){
    h2_t h; h.x=(_Float16)a; h.y=(_Float16)b; return __builtin_bit_cast(float,h);
}
__device__ __forceinline__ float dot2c(float wc,float ac,float acc){
    return __builtin_amdgcn_fdot2(__builtin_bit_cast(h2_t,wc),__builtin_bit_cast(h2_t,ac),acc,false);
}
__device__ __forceinline__ float dot2q(float4 wq,float4 aq,float acc){
    acc=dot2c(wq.x,aq.x,acc); acc=dot2c(wq.y,aq.y,acc);
    acc=dot2c(wq.z,aq.z,acc); acc=dot2c(wq.w,aq.w,acc); return acc;
}
#define DOT4(acc,Wv,Av) acc += (Wv).x*(Av).x + (Wv).y*(Av).y + (Wv).z*(Av).z + (Wv).w*(Av).w
#define PIN4(q) asm volatile("" : "+v"((q).x), "+v"((q).y), "+v"((q).z), "+v"((q).w))

// G=2 elements per 512-thread block; 2 waves/SIMD -> VGPR cap 256 (kernel needs ~108).
__global__ __launch_bounds__(512, 1)
void ncde_solve(const float* __restrict__ ts, const float* __restrict__ x,
                const float* __restrict__ W0, const float* __restrict__ b0,
                const float* __restrict__ W1, const float* __restrict__ b1,
                const float* __restrict__ W2, const float* __restrict__ b2,
                const float* __restrict__ V0, const float* __restrict__ c0,
                const float* __restrict__ V1, const float* __restrict__ c1,
                const float* __restrict__ V2, const float* __restrict__ c2,
                const float* __restrict__ R, const float* __restrict__ rb,
                float* __restrict__ out)
{
    const int g   = threadIdx.x >> 8;        // group (batch element within block)
    const int tid = threadIdx.x & 255;       // thread within group
    const int b   = blockIdx.x * GG + g;
    const int row2 = tid >> 1, half = tid & 1;         // rows 0..127, K halved
    const int row4 = 128 + (tid >> 2), quad = tid & 3; // V2 rows 128..191, K quartered
    const int prow = tid >> 3, poct = tid & 7;         // projection

    __shared__ __align__(16) float RSh[OUTD*64];       // shared across groups (read-only)
    __shared__ __align__(16) float ySh[GG][64], k1Sh[GG][64];
    __shared__ __align__(16) float yp[GG][32], y2p[GG][32];     // y: 64 packed halves
    __shared__ __align__(16) float a0p[GG][64], a1p[GG][64];    // 128 packed halves each
    __shared__ __align__(16) float mp[GG][96];                  // 192 packed halves
    __shared__ __align__(16) float u0p[GG][3][64], u1p[GG][3][64];
    __shared__ float mSh[GG][192];
    __shared__ float JfSh[GG][3][192];
    __shared__ float slopesSh[GG][NW][6];
    __shared__ float dtsSh[GG][NSTEP];

    // ---- fp16-packed weight carriers in registers: 24 float4 = 96 VGPRs ----
    float4 v0p4[4];  // V0 half-row  (32 halves)
    float4 v1p4[8];  // V1 half-row  (64 halves)
    float4 v2p4[8];  // V2 rows 0..127 half-row (64 halves)
    float4 v2q4[4];  // V2 rows 128..191 quarter-row (32 halves), rotated groups
    {
        const float4* p0 = (const float4*)(V0 + row2*64 + half*32);
        #pragma unroll
        for (int k=0;k<4;k++){
            float4 a=p0[2*k], c=p0[2*k+1];
            float4 r; r.x=pack2(a.x,a.y); r.y=pack2(a.z,a.w); r.z=pack2(c.x,c.y); r.w=pack2(c.z,c.w);
            v0p4[k]=r;
        }
        const float4* p1 = (const float4*)(V1 + row2*128 + half*64);
        #pragma unroll
        for (int k=0;k<8;k++){
            float4 a=p1[2*k], c=p1[2*k+1];
            float4 r; r.x=pack2(a.x,a.y); r.y=pack2(a.z,a.w); r.z=pack2(c.x,c.y); r.w=pack2(c.z,c.w);
            v1p4[k]=r;
        }
        const float4* p2 = (const float4*)(V2 + row2*128 + half*64);
        #pragma unroll
        for (int k=0;k<8;k++){
            float4 a=p2[2*k], c=p2[2*k+1];
            float4 r; r.x=pack2(a.x,a.y); r.y=pack2(a.z,a.w); r.z=pack2(c.x,c.y); r.w=pack2(c.z,c.w);
            v2p4[k]=r;
        }
        #pragma unroll
        for (int j=0;j<4;j++){
            int gr=(quad+j)&3;
            const float4* pg = (const float4*)(V2 + row4*128 + quad*32 + gr*8);
            float4 a=pg[0], c=pg[1];
            float4 r; r.x=pack2(a.x,a.y); r.y=pack2(a.z,a.w); r.z=pack2(c.x,c.y); r.w=pack2(c.z,c.w);
            v2q4[j]=r;
        }
        #pragma unroll
        for (int k=0;k<4;k++) PIN4(v0p4[k]);
        #pragma unroll
        for (int k=0;k<8;k++) PIN4(v1p4[k]);
        #pragma unroll
        for (int k=0;k<8;k++) PIN4(v2p4[k]);
        #pragma unroll
        for (int k=0;k<4;k++) PIN4(v2q4[k]);
    }
    const float c0r = c0[row2], c1r = c1[row2], c2a = c2[row2], c2b = c2[row4];
    const float rbp = rb[prow];

    for (int i=threadIdx.x; i<OUTD*64; i+=512) RSh[i] = R[i];
    const float* tsb = ts + b*TT;
    for (int i=tid; i<NSTEP; i+=256) dtsSh[g][i] = tsb[i+1] - tsb[i];

    // ---- log-signature slopes (16 lanes per group) ----
    if (tid < NW) {
        const int w = tid;
        const float* xs = x + (size_t)(b*TT + w*WINW)*3;
        float x0c[3] = {xs[0], xs[1], xs[2]};
        float prev[3] = {x0c[0], x0c[1], x0c[2]};
        float am01=0.f, am02=0.f, am12=0.f, am10=0.f, am20=0.f, am21=0.f;
        #pragma unroll
        for (int k=0;k<WINW;k++) {
            float cur[3] = {xs[(k+1)*3+0], xs[(k+1)*3+1], xs[(k+1)*3+2]};
            float rel[3], dv[3];
            #pragma unroll
            for (int c=0;c<3;c++){ rel[c]=prev[c]-x0c[c]; dv[c]=cur[c]-prev[c]; }
            am01 += rel[0]*dv[1]; am10 += rel[1]*dv[0];
            am02 += rel[0]*dv[2]; am20 += rel[2]*dv[0];
            am12 += rel[1]*dv[2]; am21 += rel[2]*dv[1];
            prev[0]=cur[0]; prev[1]=cur[1]; prev[2]=cur[2];
        }
        const float invden = 1.f/(tsb[(w+1)*WINW] - tsb[w*WINW]);
        slopesSh[g][w][0] = (prev[0]-x0c[0])*invden;
        slopesSh[g][w][1] = (prev[1]-x0c[1])*invden;
        slopesSh[g][w][2] = (prev[2]-x0c[2])*invden;
        slopesSh[g][w][3] = 0.5f*(am01-am10)*invden;
        slopesSh[g][w][4] = 0.5f*(am02-am20)*invden;
        slopesSh[g][w][5] = 0.5f*(am12-am21)*invden;
    }

    // ---- h0 = init_mlp(x[b,0,:]) (one-time, fp32, global-streamed; mSh/JfSh as scratch) ----
    if (tid < 128) {
        const float xv0 = x[(size_t)b*TT*3+0];
        const float xv1 = x[(size_t)b*TT*3+1];
        const float xv2 = x[(size_t)b*TT*3+2];
        float acc = b0[tid] + W0[tid*3]*xv0 + W0[tid*3+1]*xv1 + W0[tid*3+2]*xv2;
        mSh[g][tid] = softplus_f(acc);
    }
    __syncthreads();
    if (tid < 128) {
        float acc = b1[tid];
        const float4* r = (const float4*)(W1 + tid*128);
        #pragma unroll 8
        for (int k=0;k<32;k++){ float4 wv=r[k]; float4 av=*(const float4*)&mSh[g][4*k]; DOT4(acc,wv,av); }
        JfSh[g][0][tid] = softplus_f(acc);
    }
    __syncthreads();
    if (tid < 64) {
        float acc = b2[tid];
        const float4* r = (const float4*)(W2 + tid*128);
        #pragma unroll 8
        for (int k=0;k<32;k++){ float4 wv=r[k]; float4 av=*(const float4*)&JfSh[g][0][4*k]; DOT4(acc,wv,av); }
        ySh[g][tid] = acc;
        float p = __shfl_xor(acc, 1, 64);
        if (!(tid & 1)) yp[g][tid>>1] = pack2(acc, p);
    }
    __syncthreads();

    // per-lane activation-derivative registers (producer lane == consumer lane)
    float sig0r=0.f, sig1r=0.f, dtanAr=0.f, dtanBr=0.f;

    // ---- F(y): fp16 inner, fp32 feedback (y, k, S7 combine) ----
    auto Feval = [&](const float* ypIn, bool first, float dt, int w) {
        // S1: z0 = V0@y + c0
        {
            float zA=0.f, zB=0.f;
            const float4* yb = (const float4*)ypIn + half*4;
            zA=dot2q(v0p4[0],yb[0],zA); zB=dot2q(v0p4[1],yb[1],zB);
            zA=dot2q(v0p4[2],yb[2],zA); zB=dot2q(v0p4[3],yb[3],zB);
            float z = zA + zB;
            z += __shfl_xor(z, 1, 64);
            z += c0r;
            float a = softplus_f(z);
            sig0r = sigmoid_f(z);
            if (!half) ((_Float16*)&a0p[g][0])[row2] = (_Float16)a;
        }
        __syncthreads();
        // S2: z1 = V1@a0 + c1
        {
            float zA=0.f, zB=0.f;
            const float4* ab = (const float4*)&a0p[g][0] + half*8;
            #pragma unroll
            for (int k=0;k<4;k++){ zA=dot2q(v1p4[k],ab[k],zA); }
            #pragma unroll
            for (int k=4;k<8;k++){ zB=dot2q(v1p4[k],ab[k],zB); }
            float z = zA + zB;
            z += __shfl_xor(z, 1, 64);
            z += c1r;
            float a = softplus_f(z);
            sig1r = sigmoid_f(z);
            if (!half) ((_Float16*)&a1p[g][0])[row2] = (_Float16)a;
        }
        __syncthreads();
        // S3: z2 = V2@a1 + c2 ; m = tanh, dtan in regs
        {
            float zA=0.f, zB=0.f;
            const float4* ab = (const float4*)&a1p[g][0] + half*8;
            #pragma unroll
            for (int k=0;k<4;k++){ zA=dot2q(v2p4[k],ab[k],zA); }
            #pragma unroll
            for (int k=4;k<8;k++){ zB=dot2q(v2p4[k],ab[k],zB); }
            float z = zA + zB;
            z += __shfl_xor(z, 1, 64);
            z += c2a;
            float mm = tanh_f(z);
            dtanAr = 1.f - mm*mm;
            if (!half){ mSh[g][row2]=mm; ((_Float16*)&mp[g][0])[row2]=(_Float16)mm; }

            float zq = 0.f;
            const float4* a4 = (const float4*)&a1p[g][0];
            #pragma unroll
            for (int j=0;j<4;j++){ zq=dot2q(v2q4[j], a4[quad*4 + ((quad+j)&3)], zq); }
            zq += __shfl_xor(zq, 1, 64);
            zq += __shfl_xor(zq, 2, 64);
            zq += c2b;
            float mq = tanh_f(zq);
            dtanBr = 1.f - mq*mq;
            if (!quad){ mSh[g][row4]=mq; ((_Float16*)&mp[g][0])[row4]=(_Float16)mq; }
        }
        __syncthreads();
        // S4: u0[d] = sig0 * (V0 @ m[d])
        {
            float t0=0.f,t1=0.f,t2=0.f;
            const float4* m0 = (const float4*)&mp[g][0] + half*4;
            const float4* m1 = (const float4*)&mp[g][0] + 8  + half*4;
            const float4* m2 = (const float4*)&mp[g][0] + 16 + half*4;
            #pragma unroll
            for (int k=0;k<4;k++){ t0=dot2q(v0p4[k],m0[k],t0); t1=dot2q(v0p4[k],m1[k],t1); t2=dot2q(v0p4[k],m2[k],t2); }
            t0 += __shfl_xor(t0,1,64);
            t1 += __shfl_xor(t1,1,64);
            t2 += __shfl_xor(t2,1,64);
            if (!half){
                ((_Float16*)&u0p[g][0][0])[row2]=(_Float16)(sig0r*t0);
                ((_Float16*)&u0p[g][1][0])[row2]=(_Float16)(sig0r*t1);
                ((_Float16*)&u0p[g][2][0])[row2]=(_Float16)(sig0r*t2);
            }
        }
        __syncthreads();
        // S5: u1[d] = sig1 * (V1 @ u0[d])
        {
            float t0=0.f,t1=0.f,t2=0.f;
            const float4* q0 = (const float4*)&u0p[g][0][0] + half*8;
            const float4* q1 = (const float4*)&u0p[g][1][0] + half*8;
            const float4* q2 = (const float4*)&u0p[g][2][0] + half*8;
            #pragma unroll
            for (int k=0;k<8;k++){ t0=dot2q(v1p4[k],q0[k],t0); t1=dot2q(v1p4[k],q1[k],t1); t2=dot2q(v1p4[k],q2[k],t2); }
            t0 += __shfl_xor(t0,1,64);
            t1 += __shfl_xor(t1,1,64);
            t2 += __shfl_xor(t2,1,64);
            if (!half){
                ((_Float16*)&u1p[g][0][0])[row2]=(_Float16)(sig1r*t0);
                ((_Float16*)&u1p[g][1][0])[row2]=(_Float16)(sig1r*t1);
                ((_Float16*)&u1p[g][2][0])[row2]=(_Float16)(sig1r*t2);
            }
        }
        __syncthreads();
        // S6: Jf[d] = dtan * (V2 @ u1[d])
        {
            float t0=0.f,t1=0.f,t2=0.f;
            const float4* q0 = (const float4*)&u1p[g][0][0] + half*8;
            const float4* q1 = (const float4*)&u1p[g][1][0] + half*8;
            const float4* q2 = (const float4*)&u1p[g][2][0] + half*8;
            #pragma unroll
            for (int k=0;k<8;k++){ t0=dot2q(v2p4[k],q0[k],t0); t1=dot2q(v2p4[k],q1[k],t1); t2=dot2q(v2p4[k],q2[k],t2); }
            t0 += __shfl_xor(t0,1,64);
            t1 += __shfl_xor(t1,1,64);
            t2 += __shfl_xor(t2,1,64);
            if (!half){
                JfSh[g][0][row2]=dtanAr*t0; JfSh[g][1][row2]=dtanAr*t1; JfSh[g][2][row2]=dtanAr*t2;
            }
            float s0=0.f,s1=0.f,s2=0.f;
            const float4* w0 = (const float4*)&u1p[g][0][0];
            const float4* w1 = (const float4*)&u1p[g][1][0];
            const float4* w2 = (const float4*)&u1p[g][2][0];
            #pragma unroll
            for (int j=0;j<4;j++){
                const int idx = quad*4 + ((quad+j)&3);
                s0=dot2q(v2q4[j],w0[idx],s0); s1=dot2q(v2q4[j],w1[idx],s1); s2=dot2q(v2q4[j],w2[idx],s2);
            }
            s0 += __shfl_xor(s0,1,64); s0 += __shfl_xor(s0,2,64);
            s1 += __shfl_xor(s1,1,64); s1 += __shfl_xor(s1,2,64);
            s2 += __shfl_xor(s2,1,64); s2 += __shfl_xor(s2,2,64);
            if (!quad){
                JfSh[g][0][row4]=dtanBr*s0; JfSh[g][1][row4]=dtanBr*s1; JfSh[g][2][row4]=dtanBr*s2;
            }
        }
        __syncthreads();
        // S7 + Heun integrate (fp32, first wave of group) + fp16 y re-pack via shfl
        if (tid < 64) {
            const int h = tid;
            const float s0=slopesSh[g][w][0], s1=slopesSh[g][w][1], s2=slopesSh[g][w][2],
                        s3=slopesSh[g][w][3], s4=slopesSh[g][w][4], s5=slopesSh[g][w][5];
            float kk = mSh[g][h]*s0 + mSh[g][64+h]*s1 + mSh[g][128+h]*s2;
            kk += s3*(JfSh[g][0][64+h]  - JfSh[g][1][h]);
            kk += s4*(JfSh[g][0][128+h] - JfSh[g][2][h]);
            kk += s5*(JfSh[g][1][128+h] - JfSh[g][2][64+h]);
            if (first){
                k1Sh[g][h] = kk;
                float y2 = ySh[g][h] + dt*kk;
                float p = __shfl_xor(y2, 1, 64);
                if (!(h&1)) y2p[g][h>>1] = pack2(y2, p);
            } else {
                float yn = ySh[g][h] + 0.5f*dt*(k1Sh[g][h] + kk);
                ySh[g][h] = yn;
                float p = __shfl_xor(yn, 1, 64);
                if (!(h&1)) yp[g][h>>1] = pack2(yn, p);
            }
        }
        __syncthreads();
    };

    // ---- Heun scan; projection of y_step overlapped with S1 phase ----
    for (int step=0; step<NSTEP; ++step) {
        {
            float pacc = 0.f;
            const float4* rr = (const float4*)(RSh + prow*64 + poct*8);
            const float4* yy = (const float4*)(&ySh[g][0] + poct*8);
            DOT4(pacc, rr[0], yy[0]); DOT4(pacc, rr[1], yy[1]);
            pacc += __shfl_xor(pacc,1,64);
            pacc += __shfl_xor(pacc,2,64);
            pacc += __shfl_xor(pacc,4,64);
            if (!poct) out[(size_t)(b*TT + step)*OUTD + prow] = tanh_f(pacc + rbp);
        }
        const float dt = dtsSh[g][step];
        const int w = step >> 3;
        Feval(&yp[g][0],  true,  dt, w);
        Feval(&y2p[g][0], false, dt, w);
    }
    {
        float pacc = 0.f;
        const float4* rr = (const float4*)(RSh + prow*64 + poct*8);
        const float4* yy = (const float4*)(&ySh[g][0] + poct*8);
        DOT4(pacc, rr[0], yy[0]); DOT4(pacc, rr[1], yy[1]);
        pacc += __shfl_xor(pacc,1,64);
        pacc += __shfl_xor(pacc,2,64);
        pacc += __shfl_xor(pacc,4,64);
        if (!poct) out[(size_t)(b*TT + NSTEP)*OUTD + prow] = tanh_f(pacc + rbp);
    }
}

extern "C" void kernel_launch(void* const* d_in, const int* in_sizes, int n_in,
                              void* d_out, int out_size, void* d_ws, size_t ws_size,
                              hipStream_t stream) {
    const float* ts = (const float*)d_in[0];
    const float* x  = (const float*)d_in[1];
    const float* W0 = (const float*)d_in[2];
    const float* b0 = (const float*)d_in[3];
    const float* W1 = (const float*)d_in[4];
    const float* b1 = (const float*)d_in[5];
    const float* W2 = (const float*)d_in[6];
    const float* b2 = (const float*)d_in[7];
    const float* V0 = (const float*)d_in[8];
    const float* c0 = (const float*)d_in[9];
    const float* V1 = (const float*)d_in[10];
    const float* c1 = (const float*)d_in[11];
    const float* V2 = (const float*)d_in[12];
    const float* c2 = (const float*)d_in[13];
    const float* R  = (const float*)d_in[14];
    const float* rb = (const float*)d_in[15];
    float* out = (float*)d_out;

    ncde_solve<<<dim3(BB/GG), dim3(256*GG), 0, stream>>>(
        ts, x, W0, b0, W1, b1, W2, b2, V0, c0, V1, c1, V2, c2, R, rb, out);
}